// Round 1
// baseline (111.500 us; speedup 1.0000x reference)
//
#include <hip/hip_runtime.h>

// Reference is ifft2(fft2(x)) with cancelling transposes == identity on the
// input tensor (up to FFT roundoff ~1e-4, threshold is 1.08e-1).
// So the kernel is a pure fp32 copy: 32*512*512*8 = 67,108,864 floats (256 MiB).
// Memory-bound: 512 MiB total traffic @ ~6.3 TB/s -> ~85 us floor.

__global__ void copy_f4_kernel(const float4* __restrict__ in,
                               float4* __restrict__ out,
                               int n4) {
    int idx = blockIdx.x * blockDim.x + threadIdx.x;
    int stride = gridDim.x * blockDim.x;
    for (int i = idx; i < n4; i += stride) {
        out[i] = in[i];
    }
}

extern "C" void kernel_launch(void* const* d_in, const int* in_sizes, int n_in,
                              void* d_out, int out_size, void* d_ws, size_t ws_size,
                              hipStream_t stream) {
    const float4* in = (const float4*)d_in[0];
    float4* out = (float4*)d_out;
    int n = in_sizes[0];          // 67,108,864 floats
    int n4 = n >> 2;              // 16,777,216 float4s

    const int block = 256;
    // Cap grid and grid-stride: 2048 blocks covers 256 CUs x 8 blocks/CU.
    int grid = (n4 + block - 1) / block;
    if (grid > 2048) grid = 2048;

    copy_f4_kernel<<<grid, block, 0, stream>>>(in, out, n4);
}